// Round 1
// baseline (1055.816 us; speedup 1.0000x reference)
//
#include <hip/hip_runtime.h>

// LSTM (B=2048, T=168, I=6, H=128) + FC(128->64, PReLU) + FC(64->1, PReLU).
// Strategy: 256 blocks x 512 threads; block b owns 8 batch rows for ALL 168
// timesteps (rows are independent -> no inter-block sync). Thread t owns gate
// row t of W_hh (128 floats) PERSISTENT IN VGPRS across the whole time loop;
// h is broadcast from LDS (same-address ds_read_b128 = conflict-free).
// All math fp32.

#define BT 512
#define RPB 8
#define T_STEPS 168
#define HID 128
#define NIN 6

__global__ __launch_bounds__(BT) void lstm_fused_kernel(
    const float* __restrict__ s_inp,   // [2048,168,5]
    const float* __restrict__ flow_x,  // [2048,168,1]
    const float* __restrict__ W_ih,    // [512,6]
    const float* __restrict__ W_hh,    // [512,128]
    const float* __restrict__ b_ih,    // [512]
    const float* __restrict__ b_hh,    // [512]
    const float* __restrict__ W1,      // [64,128]
    const float* __restrict__ b1,      // [64]
    const float* __restrict__ a1p,     // [1]
    const float* __restrict__ W2,      // [1,64]
    const float* __restrict__ b2,      // [1]
    const float* __restrict__ a2p,     // [1]
    float* __restrict__ out)           // [2048]
{
    __shared__ float h_lds[RPB][HID];
    __shared__ float c_lds[RPB][HID];
    __shared__ float g_lds[RPB][4 * HID];
    __shared__ float xs[RPB][8];
    __shared__ float y1[RPB][64];

    const int t = threadIdx.x;            // 0..511 == gate row index
    const int row_base = blockIdx.x * RPB;

    // ---- persistent per-thread weights (128 VGPRs for W_hh row t) ----
    float4 wv[HID / 4];
    const float4* W4 = reinterpret_cast<const float4*>(W_hh);
    #pragma unroll
    for (int q = 0; q < HID / 4; ++q) wv[q] = W4[(size_t)t * (HID / 4) + q];

    float xw[NIN];
    #pragma unroll
    for (int i = 0; i < NIN; ++i) xw[i] = W_ih[t * NIN + i];

    const float bias = b_ih[t] + b_hh[t];
    const int gtype = t >> 7;  // 0:i(sig) 1:f(sig) 2:g(tanh) 3:o(sig)

    // ---- zero init h, c ----
    for (int idx = t; idx < RPB * HID; idx += BT) {
        (&h_lds[0][0])[idx] = 0.f;
        (&c_lds[0][0])[idx] = 0.f;
    }

    for (int s = 0; s < T_STEPS; ++s) {
        // (A) stage x[rows, s, 0:6] into LDS
        if (t < RPB * NIN) {
            int r = t / NIN, i = t % NIN;
            int row = row_base + r;
            float v = (i < 5) ? s_inp[((size_t)row * T_STEPS + s) * 5 + i]
                              : flow_x[(size_t)row * T_STEPS + s];
            xs[r][i] = v;
        }
        __syncthreads();  // xs ready; h from previous pointwise ready

        // (C) gates[r][t] = act( bias + x.Wih + h.Whh ), all from regs/LDS-bcast
        #pragma unroll
        for (int r = 0; r < RPB; ++r) {
            float acc = bias;
            #pragma unroll
            for (int i = 0; i < NIN; ++i) acc += xs[r][i] * xw[i];
            const float4* h4 = reinterpret_cast<const float4*>(h_lds[r]);
            #pragma unroll
            for (int q = 0; q < HID / 4; ++q) {
                float4 hv = h4[q];
                acc += hv.x * wv[q].x + hv.y * wv[q].y
                     + hv.z * wv[q].z + hv.w * wv[q].w;
            }
            float val = (gtype == 2) ? tanhf(acc)
                                     : 1.f / (1.f + expf(-acc));
            g_lds[r][t] = val;
        }
        __syncthreads();  // gates ready

        // (E) pointwise c/h update: 1024 (r,channel) items over 512 threads
        #pragma unroll
        for (int q = 0; q < 2; ++q) {
            int item = t + q * BT;
            int r = item >> 7, j = item & (HID - 1);
            float gi = g_lds[r][j];
            float gf = g_lds[r][HID + j];
            float gg = g_lds[r][2 * HID + j];
            float go = g_lds[r][3 * HID + j];
            float c = gf * c_lds[r][j] + gi * gg;
            c_lds[r][j] = c;
            h_lds[r][j] = go * tanhf(c);
        }
        // no barrier here: next iteration's first barrier orders E -> C'
    }
    __syncthreads();  // final h ready

    // ---- FC1: [8,128] @ W1^T[128,64] + b1, PReLU ----
    {
        int r = t >> 6, j = t & 63;
        const float4* w14 = reinterpret_cast<const float4*>(W1 + j * HID);
        const float4* h4 = reinterpret_cast<const float4*>(h_lds[r]);
        float acc = b1[j];
        #pragma unroll
        for (int q = 0; q < HID / 4; ++q) {
            float4 a = h4[q], b = w14[q];
            acc += a.x * b.x + a.y * b.y + a.z * b.z + a.w * b.w;
        }
        float av = a1p[0];
        y1[r][j] = (acc >= 0.f) ? acc : av * acc;
    }
    __syncthreads();

    // ---- FC2: [8,64] @ W2^T[64,1] + b2, PReLU ----
    if (t < RPB) {
        const float4* w24 = reinterpret_cast<const float4*>(W2);
        const float4* y4 = reinterpret_cast<const float4*>(y1[t]);
        float acc = 0.f;
        #pragma unroll
        for (int q = 0; q < 64 / 4; ++q) {
            float4 a = y4[q], b = w24[q];
            acc += a.x * b.x + a.y * b.y + a.z * b.z + a.w * b.w;
        }
        acc += b2[0];
        float av = a2p[0];
        out[row_base + t] = (acc >= 0.f) ? acc : av * acc;
    }
}

extern "C" void kernel_launch(void* const* d_in, const int* in_sizes, int n_in,
                              void* d_out, int out_size, void* d_ws, size_t ws_size,
                              hipStream_t stream) {
    const float* s_inp  = (const float*)d_in[0];
    const float* flow_x = (const float*)d_in[1];
    const float* W_ih   = (const float*)d_in[2];
    const float* W_hh   = (const float*)d_in[3];
    const float* b_ih   = (const float*)d_in[4];
    const float* b_hh   = (const float*)d_in[5];
    const float* W1     = (const float*)d_in[6];
    const float* b1     = (const float*)d_in[7];
    const float* a1     = (const float*)d_in[8];
    const float* W2     = (const float*)d_in[9];
    const float* b2     = (const float*)d_in[10];
    const float* a2     = (const float*)d_in[11];
    float* out = (float*)d_out;

    dim3 grid(2048 / RPB);   // 256 blocks, 8 rows each
    dim3 block(BT);
    lstm_fused_kernel<<<grid, block, 0, stream>>>(
        s_inp, flow_x, W_ih, W_hh, b_ih, b_hh, W1, b1, a1, W2, b2, a2, out);
}

// Round 2
// 368.025 us; speedup vs baseline: 2.8689x; 2.8689x over previous
//
#include <hip/hip_runtime.h>

// LSTM (B=2048, T=168, I=6, H=128) + FC(128->64, PReLU) + FC(64->1, PReLU).
// MFMA bf16x3 (hi/lo split) version.
// 256 blocks x 512 threads (8 waves); block owns 8 batch rows for all 168
// steps. Wave w owns gate columns [w*64, w*64+64) as register-resident
// B-fragments (hi+lo bf16, K padded to 160: 128 h + 6 x + 1 bias + 25 zero).
// Per step: h (bf16 hi/lo, XOR-swizzled LDS) -> A-frags -> 60 MFMA ->
// activations -> g_lds -> pointwise c/h update (c in regs) -> h back to LDS.

typedef __attribute__((ext_vector_type(8))) short short8;
typedef __attribute__((ext_vector_type(4))) float f32x4;

#define BT 512
#define TS 168
#define HID 128
#define ROWSTR 192   // padded LDS row stride (bf16 elements); 384 bytes
#define NKK 5        // K = 5*32 = 160
#define NNT 4        // n-tiles per wave (4*16 = 64 gate cols)

__device__ __forceinline__ ushort bf_hi(float v) {
    return (ushort)(__float_as_uint(v) >> 16);
}
__device__ __forceinline__ ushort bf_lo(float v) {
    unsigned h = __float_as_uint(v) & 0xFFFF0000u;
    float l = v - __uint_as_float(h);
    return (ushort)(__float_as_uint(l) >> 16);
}
__device__ __forceinline__ float sigm_f(float x) { return 1.f / (1.f + __expf(-x)); }
__device__ __forceinline__ float tanh_f(float x) { return 1.f - 2.f / (__expf(2.f * x) + 1.f); }

__global__ __launch_bounds__(BT, 2) void lstm_mfma_kernel(
    const float* __restrict__ s_inp,   // [2048,168,5]
    const float* __restrict__ flow_x,  // [2048,168,1]
    const float* __restrict__ W_ih,    // [512,6]
    const float* __restrict__ W_hh,    // [512,128]
    const float* __restrict__ b_ih,    // [512]
    const float* __restrict__ b_hh,    // [512]
    const float* __restrict__ W1,      // [64,128]
    const float* __restrict__ b1,      // [64]
    const float* __restrict__ a1p,     // [1]
    const float* __restrict__ W2,      // [1,64]
    const float* __restrict__ b2,      // [1]
    const float* __restrict__ a2p,     // [1]
    float* __restrict__ out)           // [2048]
{
    __shared__ float xs[8][TS][6];                  // 32256 B
    __shared__ float g_lds[8][512];                 // 16384 B (also reused for final h f32)
    __shared__ __align__(16) ushort hhi[16 * ROWSTR];  // 6144 B
    __shared__ __align__(16) ushort hlo[16 * ROWSTR];  // 6144 B
    __shared__ float y1s[8][64];                    // 2048 B   (total ~63 KB < 64 KB)

    const int t = threadIdx.x;
    const int w = t >> 6;          // wave 0..7
    const int l = t & 63;          // lane
    const int l15 = l & 15;
    const int l4 = l >> 4;         // 0..3
    const int row_base = blockIdx.x * 8;

    // ---- register-resident B fragments (weights, hi/lo bf16) ----
    // lane holds B[k][g] for g = w*64 + nt*16 + l15, k = kk*32 + l4*8 + j
    short8 Bh[NKK][NNT], Bl[NKK][NNT];
    {
        const int g = w * 64 /*wave base*/;
        #pragma unroll
        for (int nt = 0; nt < NNT; ++nt) {
            int gc = g + nt * 16 + l15;
            float bias = b_ih[gc] + b_hh[gc];
            #pragma unroll
            for (int kk = 0; kk < NKK; ++kk) {
                #pragma unroll
                for (int j = 0; j < 8; ++j) {
                    int k = kk * 32 + l4 * 8 + j;
                    float v;
                    if (k < HID)            v = W_hh[gc * HID + k];
                    else if (k < HID + 6)   v = W_ih[gc * 6 + (k - HID)];
                    else if (k == HID + 6)  v = bias;
                    else                    v = 0.f;
                    Bh[kk][nt][j] = (short)bf_hi(v);
                    Bl[kk][nt][j] = (short)bf_lo(v);
                }
            }
        }
    }

    // ---- stage all x for this block's 8 rows into LDS (coalesced) ----
    for (int idx = t; idx < 8 * TS * 5; idx += BT) {
        int r = idx / (TS * 5), rem = idx % (TS * 5);
        xs[r][rem / 5][rem % 5] = s_inp[(size_t)row_base * (TS * 5) + idx];
    }
    for (int idx = t; idx < 8 * TS; idx += BT) {
        xs[idx / TS][idx % TS][5] = flow_x[(size_t)row_base * TS + idx];
    }
    // zero h arrays (rows 8..15 stay zero forever)
    for (int idx = t; idx < 16 * ROWSTR; idx += BT) { hhi[idx] = 0; hlo[idx] = 0; }
    __syncthreads();

    // bias column (k=134) = 1.0 for all 16 rows; x(0) for rows 0..7
    if (t < 16) {
        int m = t;
        int byte = (2 * 134) ^ ((m & 7) << 4);
        hhi[m * ROWSTR + byte / 2] = 0x3F80;  // 1.0 in bf16; lo stays 0
    }
    const int xr = t / 6, xi = t - (t / 6) * 6;      // valid for t < 48
    if (t < 48) {
        float v = xs[xr][0][xi];
        int byte = (2 * (HID + xi)) ^ ((xr & 7) << 4);
        hhi[xr * ROWSTR + byte / 2] = bf_hi(v);
        hlo[xr * ROWSTR + byte / 2] = bf_lo(v);
    }

    // ---- per-step constant addresses ----
    // A-frag read: m = l15, elem offset = (kk*64 + l4*16) ^ ((m&7)<<4) bytes
    const int a_base = l15 * ROWSTR;
    const int a_swz = (l15 & 7) << 4;
    const int a_hi16 = l4 * 16;
    // pointwise: thread owns (row pr, cols pj, pj+1)
    const int pr = t >> 6;
    const int pj = (t & 63) * 2;
    const int hw_idx = pr * ROWSTR + (((4 * (t & 63)) ^ (pr << 4)) >> 1); // ushort units
    const int xw_idx = (t < 48) ? (xr * ROWSTR + (((2 * (HID + xi)) ^ ((xr & 7) << 4)) >> 1)) : 0;
    const bool is_tanh = ((w >> 1) == 2);  // waves 4,5 hold gate 'g' (tanh)

    float c0 = 0.f, c1 = 0.f, h0f = 0.f, h1f = 0.f;

    for (int s = 0; s < TS; ++s) {
        __syncthreads();  // B1: h(s)/x(s) writes visible

        f32x4 acc[NNT];
        #pragma unroll
        for (int nt = 0; nt < NNT; ++nt) acc[nt] = (f32x4){0.f, 0.f, 0.f, 0.f};

        #pragma unroll
        for (int kk = 0; kk < NKK; ++kk) {
            int off = ((kk * 64 + a_hi16) ^ a_swz) >> 1;  // ushort units, 16B aligned
            short8 ah = *(const short8*)(hhi + a_base + off);
            short8 al = *(const short8*)(hlo + a_base + off);
            #pragma unroll
            for (int nt = 0; nt < NNT; ++nt)
                acc[nt] = __builtin_amdgcn_mfma_f32_16x16x32_bf16(ah, Bh[kk][nt], acc[nt], 0, 0, 0);
            #pragma unroll
            for (int nt = 0; nt < NNT; ++nt)
                acc[nt] = __builtin_amdgcn_mfma_f32_16x16x32_bf16(ah, Bl[kk][nt], acc[nt], 0, 0, 0);
            #pragma unroll
            for (int nt = 0; nt < NNT; ++nt)
                acc[nt] = __builtin_amdgcn_mfma_f32_16x16x32_bf16(al, Bh[kk][nt], acc[nt], 0, 0, 0);
        }

        // activation + gate write: D col = lane&15 (gate), row = l4*4+reg (batch row)
        if (l < 32) {
            if (is_tanh) {
                #pragma unroll
                for (int nt = 0; nt < NNT; ++nt) {
                    int gcol = w * 64 + nt * 16 + l15;
                    #pragma unroll
                    for (int reg = 0; reg < 4; ++reg)
                        g_lds[l4 * 4 + reg][gcol] = tanh_f(acc[nt][reg]);
                }
            } else {
                #pragma unroll
                for (int nt = 0; nt < NNT; ++nt) {
                    int gcol = w * 64 + nt * 16 + l15;
                    #pragma unroll
                    for (int reg = 0; reg < 4; ++reg)
                        g_lds[l4 * 4 + reg][gcol] = sigm_f(acc[nt][reg]);
                }
            }
        }
        __syncthreads();  // B2: gates visible

        // pointwise c/h update (c persistent in regs)
        float2 gi = *(const float2*)&g_lds[pr][pj];
        float2 gf = *(const float2*)&g_lds[pr][128 + pj];
        float2 gg = *(const float2*)&g_lds[pr][256 + pj];
        float2 go = *(const float2*)&g_lds[pr][384 + pj];
        c0 = gf.x * c0 + gi.x * gg.x;
        c1 = gf.y * c1 + gi.y * gg.y;
        h0f = go.x * tanh_f(c0);
        h1f = go.y * tanh_f(c1);
        // split h -> bf16 hi/lo, pack pairs, one b32 store each
        {
            unsigned u0 = __float_as_uint(h0f), u1 = __float_as_uint(h1f);
            unsigned h0h = u0 & 0xFFFF0000u, h1h = u1 & 0xFFFF0000u;
            unsigned hi2 = (h0h >> 16) | h1h;
            float l0 = h0f - __uint_as_float(h0h);
            float l1 = h1f - __uint_as_float(h1h);
            unsigned lo2 = (__float_as_uint(l0) >> 16) | (__float_as_uint(l1) & 0xFFFF0000u);
            *(unsigned*)(hhi + hw_idx) = hi2;
            *(unsigned*)(hlo + hw_idx) = lo2;
        }
        // stage x(s+1)
        if (t < 48 && s + 1 < TS) {
            float v = xs[xr][s + 1][xi];
            hhi[xw_idx] = bf_hi(v);
            hlo[xw_idx] = bf_lo(v);
        }
    }
    __syncthreads();

    // ---- FC head ----
    // reuse g_lds rows as final h f32 [8][128]
    g_lds[pr][pj] = h0f;
    g_lds[pr][pj + 1] = h1f;
    __syncthreads();

    {
        int r = t >> 6, jj = t & 63;
        const float4* wrow = (const float4*)(W1 + jj * HID);
        const float4* hr = (const float4*)&g_lds[r][0];
        float acc = b1[jj];
        #pragma unroll
        for (int q = 0; q < HID / 4; ++q) {
            float4 a = hr[q], b = wrow[q];
            acc += a.x * b.x + a.y * b.y + a.z * b.z + a.w * b.w;
        }
        float av = a1p[0];
        y1s[r][jj] = (acc >= 0.f) ? acc : av * acc;
    }
    __syncthreads();

    if (t < 8) {
        const float4* w2 = (const float4*)W2;
        const float4* yr = (const float4*)&y1s[t][0];
        float acc = 0.f;
        #pragma unroll
        for (int q = 0; q < 64 / 4; ++q) {
            float4 a = yr[q], b = w2[q];
            acc += a.x * b.x + a.y * b.y + a.z * b.z + a.w * b.w;
        }
        acc += b2[0];
        float av = a2p[0];
        out[row_base + t] = (acc >= 0.f) ? acc : av * acc;
    }
}

extern "C" void kernel_launch(void* const* d_in, const int* in_sizes, int n_in,
                              void* d_out, int out_size, void* d_ws, size_t ws_size,
                              hipStream_t stream) {
    const float* s_inp  = (const float*)d_in[0];
    const float* flow_x = (const float*)d_in[1];
    const float* W_ih   = (const float*)d_in[2];
    const float* W_hh   = (const float*)d_in[3];
    const float* b_ih   = (const float*)d_in[4];
    const float* b_hh   = (const float*)d_in[5];
    const float* W1     = (const float*)d_in[6];
    const float* b1     = (const float*)d_in[7];
    const float* a1     = (const float*)d_in[8];
    const float* W2     = (const float*)d_in[9];
    const float* b2     = (const float*)d_in[10];
    const float* a2     = (const float*)d_in[11];
    float* out = (float*)d_out;

    dim3 grid(2048 / 8);   // 256 blocks, 8 rows each -> 1 block/CU
    dim3 block(BT);
    lstm_mfma_kernel<<<grid, block, 0, stream>>>(
        s_inp, flow_x, W_ih, W_hh, b_ih, b_hh, W1, b1, a1, W2, b2, a2, out);
}

// Round 5
// 253.119 us; speedup vs baseline: 4.1712x; 1.4540x over previous
//
#include <hip/hip_runtime.h>

// LSTM (B=2048, T=168, I=6, H=128) + FC(128->64, PReLU) + FC(64->1, PReLU).
// MFMA bf16 4-term split, ONE barrier per step.
// 256 blocks x 512 threads (8 waves); block owns 8 batch rows for all 168 steps.
// A-tile (16x160): rows 0-7 = h hi-bf16, rows 8-15 = h lo-bf16 (+x, +bias col).
// Wave w owns B-cols {gate*128 + w*16 + l15 : gate=0..3} as register-resident
// hi/lo fragments. Two MFMA sets (A x Bh, A x Bl) give all 4 split products.
// shfl_xor(32) folds lo-rows into hi-rows -> each lane holds i,f,g,o for its
// 2 (row,ch) pairs -> in-lane activation + c update (c in regs) -> h hi/lo
// written back to the A-array. No gate LDS buffer, no second barrier.
// (2nd resubmission: container unresponsive twice, kernel never executed.)

typedef __attribute__((ext_vector_type(8))) short short8;
typedef __attribute__((ext_vector_type(4))) float f32x4;

#define BT 512
#define TS 168
#define HID 128
#define ROWSTR 192   // A-array row stride in ushorts (384 B)
#define NKK 5        // K = 5*32 = 160 (128 h + 6 x + 1 bias + 25 zero)
#define NNT 4        // 4 gate tiles per wave

__device__ __forceinline__ ushort bf_hi(float v) {
    return (ushort)(__float_as_uint(v) >> 16);
}
__device__ __forceinline__ ushort bf_lo(float v) {
    unsigned h = __float_as_uint(v) & 0xFFFF0000u;
    float l = v - __uint_as_float(h);
    return (ushort)(__float_as_uint(l) >> 16);
}
// fast activations: native v_exp_f32 + v_rcp_f32 (~1 ulp, far below tolerance)
__device__ __forceinline__ float sigm_f(float x) {
    return __fdividef(1.f, 1.f + __expf(-x));
}
__device__ __forceinline__ float tanh_f(float x) {
    return 1.f - __fdividef(2.f, __expf(2.f * x) + 1.f);
}

__global__ __launch_bounds__(BT, 2) void lstm_mfma3_kernel(
    const float* __restrict__ s_inp,   // [2048,168,5]
    const float* __restrict__ flow_x,  // [2048,168,1]
    const float* __restrict__ W_ih,    // [512,6]
    const float* __restrict__ W_hh,    // [512,128]
    const float* __restrict__ b_ih,    // [512]
    const float* __restrict__ b_hh,    // [512]
    const float* __restrict__ W1,      // [64,128]
    const float* __restrict__ b1,      // [64]
    const float* __restrict__ a1p,     // [1]
    const float* __restrict__ W2,      // [1,64]
    const float* __restrict__ b2,      // [1]
    const float* __restrict__ a2p,     // [1]
    float* __restrict__ out)           // [2048]
{
    __shared__ float xs[8][TS][6];                     // 32256 B
    __shared__ __align__(16) ushort hA[16 * ROWSTR];   // 6144 B
    __shared__ float y1s[8][64];                       // 2048 B

    const int t = threadIdx.x;
    const int w = t >> 6;       // wave 0..7
    const int l = t & 63;
    const int l15 = l & 15;
    const int l4 = l >> 4;      // 0..3
    const int row_base = blockIdx.x * 8;

    // ---- register-resident B fragments (hi/lo bf16) ----
    // lane holds B[k][gc] for gc = nt*128 + w*16 + l15 (gate nt, channel w*16+l15),
    // k = kk*32 + l4*8 + j  (same k-map as the A-frag read below).
    short8 Bh[NKK][NNT], Bl[NKK][NNT];
    #pragma unroll
    for (int nt = 0; nt < NNT; ++nt) {
        const int gc = nt * HID + w * 16 + l15;
        const float bias = b_ih[gc] + b_hh[gc];
        #pragma unroll
        for (int kk = 0; kk < NKK; ++kk) {
            #pragma unroll
            for (int j = 0; j < 8; ++j) {
                int k = kk * 32 + l4 * 8 + j;
                float v;
                if (k < HID)           v = W_hh[gc * HID + k];
                else if (k < HID + 6)  v = W_ih[gc * 6 + (k - HID)];
                else if (k == HID + 6) v = bias;
                else                   v = 0.f;
                Bh[kk][nt][j] = (short)bf_hi(v);
                Bl[kk][nt][j] = (short)bf_lo(v);
            }
        }
    }

    // ---- stage x for this block's 8 rows into LDS (coalesced) ----
    for (int idx = t; idx < 8 * TS * 5; idx += BT) {
        int r = idx / (TS * 5), rem = idx % (TS * 5);
        xs[r][rem / 5][rem % 5] = s_inp[(size_t)row_base * (TS * 5) + idx];
    }
    for (int idx = t; idx < 8 * TS; idx += BT) {
        xs[idx / TS][idx % TS][5] = flow_x[(size_t)row_base * TS + idx];
    }
    // zero A-array
    for (int idx = t; idx < 16 * ROWSTR / 2; idx += BT)
        ((unsigned*)hA)[idx] = 0u;
    __syncthreads();

    // bias column (k=134) = 1.0 in hi rows (lo rows stay 0)
    if (t < 8) {
        int byte = (2 * 134) ^ ((t & 7) << 4);
        hA[t * ROWSTR + (byte >> 1)] = 0x3F80;
    }
    // x(0) staging: threads 0-47 write hi plane, 64-111 write lo plane
    const bool xhi = (t < 48);
    const bool xlo = (t >= 64 && t < 112);
    const int xu = xhi ? t : (t - 64);
    const int xr = (xu < 48) ? (xu / 6) : 0;
    const int xi = (xu < 48) ? (xu % 6) : 0;
    const int xw_idx = ((xhi ? xr : xr + 8) * ROWSTR) +
                       (((2 * (HID + xi)) ^ ((xr & 7) << 4)) >> 1);
    if (xhi | xlo) {
        float v = xs[xr][0][xi];
        hA[xw_idx] = xhi ? bf_hi(v) : bf_lo(v);
    }

    // ---- per-step constants ----
    const int a_base = l15 * ROWSTR;
    const int a_swz = (l15 & 7) << 4;
    const int ch = w * 16 + l15;                    // this lane's channel
    const bool lowhalf = (l < 32);
    const int rbase = (l4 & 1) * 4 + (lowhalf ? 0 : 2);  // lane's 2 rows: rbase, rbase+1
    const int row0 = rbase, row1 = rbase + 1;
    const int cb0 = (2 * ch) ^ ((row0 & 7) << 4);
    const int cb1 = (2 * ch) ^ ((row1 & 7) << 4);
    const int hw00 = row0 * ROWSTR + (cb0 >> 1);        // h hi
    const int hw01 = (row0 + 8) * ROWSTR + (cb0 >> 1);  // h lo
    const int hw10 = row1 * ROWSTR + (cb1 >> 1);
    const int hw11 = (row1 + 8) * ROWSTR + (cb1 >> 1);

    float c0 = 0.f, c1 = 0.f, h0f = 0.f, h1f = 0.f;

    for (int s = 0; s < TS; ++s) {
        __syncthreads();  // h(s)/x(s) writes visible

        f32x4 D1[NNT], D2[NNT];
        #pragma unroll
        for (int nt = 0; nt < NNT; ++nt) {
            D1[nt] = (f32x4){0.f, 0.f, 0.f, 0.f};
            D2[nt] = (f32x4){0.f, 0.f, 0.f, 0.f};
        }

        #pragma unroll
        for (int kk = 0; kk < NKK; ++kk) {
            int off = ((kk * 64 + l4 * 16) ^ a_swz) >> 1;  // ushort units
            short8 a = *(const short8*)(hA + a_base + off);
            #pragma unroll
            for (int nt = 0; nt < NNT; ++nt)
                D1[nt] = __builtin_amdgcn_mfma_f32_16x16x32_bf16(a, Bh[kk][nt], D1[nt], 0, 0, 0);
            #pragma unroll
            for (int nt = 0; nt < NNT; ++nt)
                D2[nt] = __builtin_amdgcn_mfma_f32_16x16x32_bf16(a, Bl[kk][nt], D2[nt], 0, 0, 0);
        }

        // fold: in-lane (hi-rows + lo-rows planes), then cross-half via shfl_xor(32)
        float gate[NNT][2];
        #pragma unroll
        for (int nt = 0; nt < NNT; ++nt) {
            f32x4 s4;
            #pragma unroll
            for (int r = 0; r < 4; ++r) s4[r] = D1[nt][r] + D2[nt][r];
            #pragma unroll
            for (int r = 0; r < 4; ++r) s4[r] += __shfl_xor(s4[r], 32, 64);
            gate[nt][0] = lowhalf ? s4[0] : s4[2];
            gate[nt][1] = lowhalf ? s4[1] : s4[3];
        }

        // in-lane activation + cell update (gate order: i, f, g, o)
        {
            float ia = sigm_f(gate[0][0]);
            float fa = sigm_f(gate[1][0]);
            float ga = tanh_f(gate[2][0]);
            float oa = sigm_f(gate[3][0]);
            c0 = fa * c0 + ia * ga;
            h0f = oa * tanh_f(c0);
        }
        {
            float ia = sigm_f(gate[0][1]);
            float fa = sigm_f(gate[1][1]);
            float ga = tanh_f(gate[2][1]);
            float oa = sigm_f(gate[3][1]);
            c1 = fa * c1 + ia * ga;
            h1f = oa * tanh_f(c1);
        }

        // write h hi/lo back into the A-array
        hA[hw00] = bf_hi(h0f);
        hA[hw01] = bf_lo(h0f);
        hA[hw10] = bf_hi(h1f);
        hA[hw11] = bf_lo(h1f);

        // stage x(s+1)
        if ((xhi | xlo) && s + 1 < TS) {
            float v = xs[xr][s + 1][xi];
            hA[xw_idx] = xhi ? bf_hi(v) : bf_lo(v);
        }
    }
    __syncthreads();  // all lanes done with xs; h final in regs

    // ---- FC head ----
    float* hfin = (float*)xs;  // reuse xs as [8][128] f32
    hfin[row0 * HID + ch] = h0f;
    hfin[row1 * HID + ch] = h1f;
    __syncthreads();

    {
        int r = t >> 6, j = t & 63;
        const float4* wrow = (const float4*)(W1 + j * HID);
        const float4* hr = (const float4*)(hfin + r * HID);
        float acc = b1[j];
        #pragma unroll
        for (int q = 0; q < HID / 4; ++q) {
            float4 a = hr[q], b = wrow[q];
            acc += a.x * b.x + a.y * b.y + a.z * b.z + a.w * b.w;
        }
        float av = a1p[0];
        y1s[r][j] = (acc >= 0.f) ? acc : av * acc;
    }
    __syncthreads();

    if (t < 8) {
        const float4* w2 = (const float4*)W2;
        const float4* yr = (const float4*)&y1s[t][0];
        float acc = 0.f;
        #pragma unroll
        for (int q = 0; q < 64 / 4; ++q) {
            float4 a = yr[q], b = w2[q];
            acc += a.x * b.x + a.y * b.y + a.z * b.z + a.w * b.w;
        }
        acc += b2[0];
        float av = a2p[0];
        out[row_base + t] = (acc >= 0.f) ? acc : av * acc;
    }
}

extern "C" void kernel_launch(void* const* d_in, const int* in_sizes, int n_in,
                              void* d_out, int out_size, void* d_ws, size_t ws_size,
                              hipStream_t stream) {
    const float* s_inp  = (const float*)d_in[0];
    const float* flow_x = (const float*)d_in[1];
    const float* W_ih   = (const float*)d_in[2];
    const float* W_hh   = (const float*)d_in[3];
    const float* b_ih   = (const float*)d_in[4];
    const float* b_hh   = (const float*)d_in[5];
    const float* b1_    = (const float*)d_in[7];
    const float* W1     = (const float*)d_in[6];
    const float* a1     = (const float*)d_in[8];
    const float* W2     = (const float*)d_in[9];
    const float* b2     = (const float*)d_in[10];
    const float* a2     = (const float*)d_in[11];
    float* out = (float*)d_out;

    dim3 grid(2048 / 8);   // 256 blocks, 8 rows each -> 1 block/CU
    dim3 block(BT);
    lstm_mfma3_kernel<<<grid, block, 0, stream>>>(
        s_inp, flow_x, W_ih, W_hh, b_ih, b_hh, W1, b1_, a1, W2, b2, a2, out);
}